// Round 3
// baseline (1630.477 us; speedup 1.0000x reference)
//
#include <hip/hip_runtime.h>
#include <cstddef>

#define N_PTS 4096
#define DIMK 1024

static constexpr float S_SCALE = 144.26950408889634f;   // 100*log2(e)
static constexpr float TWO_S   = 288.53900817779268f;   // 200*log2(e)
static constexpr float NEG_BIG = -3.4e38f;

// ws layout (floats): [0..4095]=f~2s (shifted)  [4096..8191]=g~2s (shifted)
// Shifted/gauged coords: D2 = -2*S*x.y ; f2s_0 = S*(1024 - ||x_i||^2).
// f2s+g2s-D2 equals the reference f+g-C exactly (gauge cancels).

__device__ __forceinline__ float4 f4max(float4 a, float4 b) {
  return make_float4(fmaxf(a.x, b.x), fmaxf(a.y, b.y), fmaxf(a.z, b.z), fmaxf(a.w, b.w));
}
// (M,S) <- merge of (M,S) and (M2,S2), componentwise online-LSE merge
__device__ __forceinline__ void msmerge(float4& M, float4& S, const float4 M2, const float4 S2) {
  float4 Mn = f4max(M, M2);
  S.x = S.x * exp2f(M.x - Mn.x) + S2.x * exp2f(M2.x - Mn.x);
  S.y = S.y * exp2f(M.y - Mn.y) + S2.y * exp2f(M2.y - Mn.y);
  S.z = S.z * exp2f(M.z - Mn.z) + S2.z * exp2f(M2.z - Mn.z);
  S.w = S.w * exp2f(M.w - Mn.w) + S2.w * exp2f(M2.w - Mn.w);
  M = Mn;
}

// ---------------- prep: f~2s init = S*(1024 - ||Xs_i||^2) ----------------
__global__ __launch_bounds__(256) void k_prep(const float* __restrict__ Xs,
                                              float* __restrict__ fvec) {
  int row  = blockIdx.x * 4 + (threadIdx.x >> 6);   // 0..4095
  int lane = threadIdx.x & 63;
  const float* src = Xs + (size_t)row * DIMK;
  float s = 0.f;
#pragma unroll
  for (int r = 0; r < 4; ++r) {
    float4 a = *(const float4*)(src + lane * 4 + r * 256);
    s += a.x * a.x + a.y * a.y + a.z * a.z + a.w * a.w;
  }
#pragma unroll
  for (int off = 32; off; off >>= 1) s += __shfl_xor(s, off);
  if (lane == 0) fvec[row] = (1024.0f - s) * S_SCALE;
}

// ---------------- fp32 tiled GEMM: D2[i][j] = -2*S*dot(Xs_i, Xt_j) ----------------
// micro-tile split 4+4 (cols tx*4 and 64+tx*4; rows ty*4 and 64+ty*4) so LDS
// b128 reads alias at most 2-way (free) instead of 4-way.
__global__ __launch_bounds__(256) void k_gemm(const float* __restrict__ A,
                                              const float* __restrict__ B,
                                              float* __restrict__ D) {
  __shared__ float As[16][132];
  __shared__ float Bs[16][132];
  const int t  = threadIdx.x;
  const int tx = t & 15, ty = t >> 4;
  const int row0 = blockIdx.y * 128, col0 = blockIdx.x * 128;
  float acc[8][8];
#pragma unroll
  for (int i = 0; i < 8; ++i)
#pragma unroll
    for (int j = 0; j < 8; ++j) acc[i][j] = 0.f;

  for (int k0 = 0; k0 < DIMK; k0 += 16) {
#pragma unroll
    for (int s2 = 0; s2 < 2; ++s2) {
      int f4i = t + s2 * 256;
      int r   = f4i >> 2;            // 0..127 tile row
      int kp  = (f4i & 3) << 2;      // 0,4,8,12
      float4 a4 = *(const float4*)(A + (size_t)(row0 + r) * DIMK + k0 + kp);
      float4 b4 = *(const float4*)(B + (size_t)(col0 + r) * DIMK + k0 + kp);
      As[kp + 0][r] = a4.x; As[kp + 1][r] = a4.y; As[kp + 2][r] = a4.z; As[kp + 3][r] = a4.w;
      Bs[kp + 0][r] = b4.x; Bs[kp + 1][r] = b4.y; Bs[kp + 2][r] = b4.z; Bs[kp + 3][r] = b4.w;
    }
    __syncthreads();
#pragma unroll
    for (int kk = 0; kk < 16; ++kk) {
      float a[8], b[8];
      *(float4*)(a)     = *(const float4*)(&As[kk][ty * 4]);
      *(float4*)(a + 4) = *(const float4*)(&As[kk][64 + ty * 4]);
      *(float4*)(b)     = *(const float4*)(&Bs[kk][tx * 4]);
      *(float4*)(b + 4) = *(const float4*)(&Bs[kk][64 + tx * 4]);
#pragma unroll
      for (int i = 0; i < 8; ++i)
#pragma unroll
        for (int j = 0; j < 8; ++j) acc[i][j] = fmaf(a[i], b[j], acc[i][j]);
    }
    __syncthreads();
  }
#pragma unroll
  for (int i = 0; i < 8; ++i) {
    int r = row0 + ((i < 4) ? (ty * 4 + i) : (64 + ty * 4 + (i - 4)));
    float* out = D + (size_t)r * N_PTS + col0;
    float4 o1, o2;
    o1.x = -TWO_S * acc[i][0]; o1.y = -TWO_S * acc[i][1];
    o1.z = -TWO_S * acc[i][2]; o1.w = -TWO_S * acc[i][3];
    o2.x = -TWO_S * acc[i][4]; o2.y = -TWO_S * acc[i][5];
    o2.z = -TWO_S * acc[i][6]; o2.w = -TWO_S * acc[i][7];
    *(float4*)(out + tx * 4)      = o1;
    *(float4*)(out + 64 + tx * 4) = o2;
  }
}

// ---------------- column LSE (g update): g_j = 12 - log2 sum_i 2^(f_i - D_ij) ----------------
// 256 blocks x 1024 threads. Block covers 16 cols; thread t: c4=t&3 (float4 of
// cols), rp=t>>2 (row phase 0..255), 16 rows/thread via coalesced float4 loads.
__global__ __launch_bounds__(1024) void k_colpass(const float* __restrict__ D,
                                                  const float* __restrict__ fvec,
                                                  float* __restrict__ gvec) {
  __shared__ float fs[N_PTS];
  __shared__ float4 MS[16][4][2];
  const int t = threadIdx.x;
  *(float4*)(fs + t * 4) = *(const float4*)(fvec + t * 4);
  __syncthreads();
  const int c4 = t & 3;
  const int rp = t >> 2;                       // 0..255
  const float* base = D + blockIdx.x * 16 + c4 * 4;
  float4 M = make_float4(NEG_BIG, NEG_BIG, NEG_BIG, NEG_BIG);
  float4 S = make_float4(0.f, 0.f, 0.f, 0.f);
#pragma unroll
  for (int h = 0; h < 2; ++h) {
    float4 v[8];
#pragma unroll
    for (int q = 0; q < 8; ++q) {
      int r = rp + (h * 8 + q) * 256;
      float4 d = *(const float4*)(base + (size_t)r * N_PTS);
      float fr = fs[r];
      v[q] = make_float4(fr - d.x, fr - d.y, fr - d.z, fr - d.w);
    }
    float4 Mc = f4max(f4max(f4max(v[0], v[1]), f4max(v[2], v[3])),
                      f4max(f4max(v[4], v[5]), f4max(v[6], v[7])));
    float4 Mn = f4max(M, Mc);
    float4 s;
    s.x = S.x * exp2f(M.x - Mn.x);
    s.y = S.y * exp2f(M.y - Mn.y);
    s.z = S.z * exp2f(M.z - Mn.z);
    s.w = S.w * exp2f(M.w - Mn.w);
#pragma unroll
    for (int q = 0; q < 8; ++q) {
      s.x += exp2f(v[q].x - Mn.x);
      s.y += exp2f(v[q].y - Mn.y);
      s.z += exp2f(v[q].z - Mn.z);
      s.w += exp2f(v[q].w - Mn.w);
    }
    M = Mn; S = s;
  }
  // butterfly across the 16 row-phases within a wave (lane bits 2..5)
#pragma unroll
  for (int off = 4; off <= 32; off <<= 1) {
    float4 M2, S2;
    M2.x = __shfl_xor(M.x, off); M2.y = __shfl_xor(M.y, off);
    M2.z = __shfl_xor(M.z, off); M2.w = __shfl_xor(M.w, off);
    S2.x = __shfl_xor(S.x, off); S2.y = __shfl_xor(S.y, off);
    S2.z = __shfl_xor(S.z, off); S2.w = __shfl_xor(S.w, off);
    msmerge(M, S, M2, S2);
  }
  const int wv = t >> 6, l = t & 63;
  if (l < 4) { MS[wv][l][0] = M; MS[wv][l][1] = S; }
  __syncthreads();
  if (t < 4) {                                 // merge 16 waves, write 4 cols
    float4 M0 = MS[0][t][0], S0 = MS[0][t][1];
#pragma unroll
    for (int w = 1; w < 16; ++w) msmerge(M0, S0, MS[w][t][0], MS[w][t][1]);
    float4 g;
    g.x = 12.0f - M0.x - log2f(S0.x);
    g.y = 12.0f - M0.y - log2f(S0.y);
    g.z = 12.0f - M0.z - log2f(S0.z);
    g.w = 12.0f - M0.w - log2f(S0.w);
    *(float4*)(gvec + blockIdx.x * 16 + t * 4) = g;
  }
}

// ---------------- row LSE (f update): f_i = 12 - log2 sum_j 2^(g_j - D_ij) ----------------
// 1024 blocks x 256 threads; one wave per row, wave-only reduction.
__global__ __launch_bounds__(256) void k_rowpass(const float* __restrict__ D,
                                                 const float* __restrict__ gvec,
                                                 float* __restrict__ fvec) {
  const int t = threadIdx.x;
  const int l = t & 63;
  const int row = blockIdx.x * 4 + (t >> 6);
  const float* rp_ = D + (size_t)row * N_PTS;
  float M = NEG_BIG, S = 0.f;
#pragma unroll
  for (int c = 0; c < 4; ++c) {
    float v[16];
#pragma unroll
    for (int q = 0; q < 4; ++q) {
      int j = l * 4 + (c * 4 + q) * 256;
      float4 d = *(const float4*)(rp_ + j);
      float4 g = *(const float4*)(gvec + j);
      v[q * 4 + 0] = g.x - d.x;
      v[q * 4 + 1] = g.y - d.y;
      v[q * 4 + 2] = g.z - d.z;
      v[q * 4 + 3] = g.w - d.w;
    }
    float Mc = v[0];
#pragma unroll
    for (int q = 1; q < 16; ++q) Mc = fmaxf(Mc, v[q]);
    float Mn = fmaxf(M, Mc);
    float s  = S * exp2f(M - Mn);
#pragma unroll
    for (int q = 0; q < 16; ++q) s += exp2f(v[q] - Mn);
    M = Mn; S = s;
  }
#pragma unroll
  for (int off = 32; off; off >>= 1) {
    float M2 = __shfl_xor(M, off);
    float S2 = __shfl_xor(S, off);
    float Mn = fmaxf(M, M2);
    S = S * exp2f(M - Mn) + S2 * exp2f(M2 - Mn);
    M = Mn;
  }
  if (l == 0) fvec[row] = 12.0f - M - log2f(S);
}

// ---------------- final: P = exp2(0.1*(f_i + g_j - D_ij)), in place ----------------
__global__ __launch_bounds__(256) void k_final(float* __restrict__ D,
                                               const float* __restrict__ fvec,
                                               const float* __restrict__ gvec) {
  size_t idx = ((size_t)blockIdx.x * 256 + threadIdx.x) * 8;
  int i = (int)(idx >> 12);
  int j = (int)(idx & (N_PTS - 1));
  float fi = fvec[i];
#pragma unroll
  for (int h = 0; h < 2; ++h) {
    float4 d  = *(float4*)(D + idx + h * 4);
    float4 g4 = *(const float4*)(gvec + j + h * 4);
    d.x = exp2f(0.1f * (fi + g4.x - d.x));
    d.y = exp2f(0.1f * (fi + g4.y - d.y));
    d.z = exp2f(0.1f * (fi + g4.z - d.z));
    d.w = exp2f(0.1f * (fi + g4.w - d.w));
    *(float4*)(D + idx + h * 4) = d;
  }
}

extern "C" void kernel_launch(void* const* d_in, const int* in_sizes, int n_in,
                              void* d_out, int out_size, void* d_ws, size_t ws_size,
                              hipStream_t stream) {
  const float* Xs = (const float*)d_in[0];
  const float* Xt = (const float*)d_in[1];
  float* D    = (float*)d_out;
  float* ws   = (float*)d_ws;
  float* fvec = ws;
  float* gvec = ws + N_PTS;

  k_prep<<<1024, 256, 0, stream>>>(Xs, fvec);
  k_gemm<<<dim3(32, 32), 256, 0, stream>>>(Xs, Xt, D);
  for (int it = 0; it < 30; ++it) {
    k_colpass<<<256, 1024, 0, stream>>>(D, fvec, gvec);
    k_rowpass<<<1024, 256, 0, stream>>>(D, gvec, fvec);
  }
  k_final<<<8192, 256, 0, stream>>>(D, fvec, gvec);
}

// Round 4
// 964.560 us; speedup vs baseline: 1.6904x; 1.6904x over previous
//
#include <hip/hip_runtime.h>
#include <cstddef>
#include <cstdint>

#define N_PTS 4096
#define DIMK 1024

typedef _Float16 half8 __attribute__((ext_vector_type(8)));
typedef float floatx4 __attribute__((ext_vector_type(4)));

static constexpr float S_SCALE = 144.26950408889634f;   // 100*log2(e)
static constexpr float TWO_S   = 288.53900817779268f;   // 200*log2(e)
static constexpr float NEG_BIG = -3.4e38f;

// ws layout (bytes):
//   [0, 16K)        fvec (f~2s, shifted/gauged)
//   [16K, 32K)      gvec
//   [32K, 32K+32M)  Ah, Al, Bh, Bl   (fp16 hi/lo splits of Xs, Xt; 8 MB each)
//   [+0,  +64M)     DT (transposed D for coalesced g-sweeps)
// Shifted/gauged coords: D2 = -2*S*x.y ; f2s_0 = S*(1024 - ||x_i||^2);
// f2s+g2s-D2 equals the reference's f+g-C exactly (gauge cancels).

// ---------------- prep: f~2s init = S*(1024 - ||Xs_i||^2) ----------------
__global__ __launch_bounds__(256) void k_prep(const float* __restrict__ Xs,
                                              float* __restrict__ fvec) {
  int row  = blockIdx.x * 4 + (threadIdx.x >> 6);
  int lane = threadIdx.x & 63;
  const float* src = Xs + (size_t)row * DIMK;
  float s = 0.f;
#pragma unroll
  for (int r = 0; r < 4; ++r) {
    float4 a = *(const float4*)(src + lane * 4 + r * 256);
    s += a.x * a.x + a.y * a.y + a.z * a.z + a.w * a.w;
  }
#pragma unroll
  for (int off = 32; off; off >>= 1) s += __shfl_xor(s, off);
  if (lane == 0) fvec[row] = (1024.0f - s) * S_SCALE;
}

// ---------------- convert: fp32 -> (hi, lo) fp16 split ----------------
// hi = RN16(x); lo = RN16(x - hi)  (x - hi exact in fp32; dropped lo*lo term
// in the 3-gemm contributes < 2^-22 relative -> negligible vs tolerance)
__global__ __launch_bounds__(256) void k_convert(const float* __restrict__ X,
                                                 _Float16* __restrict__ H,
                                                 _Float16* __restrict__ L) {
  size_t i8 = ((size_t)blockIdx.x * 256 + threadIdx.x) * 8;
  float4 a = *(const float4*)(X + i8);
  float4 b = *(const float4*)(X + i8 + 4);
  float v[8] = {a.x, a.y, a.z, a.w, b.x, b.y, b.z, b.w};
  half8 h, l;
#pragma unroll
  for (int q = 0; q < 8; ++q) {
    _Float16 hh = (_Float16)v[q];
    h[q] = hh;
    l[q] = (_Float16)(v[q] - (float)hh);
  }
  *(half8*)(H + i8) = h;
  *(half8*)(L + i8) = l;
}

// ---------------- MFMA split-fp16 GEMM: D = -2S * (Ah+Al).(Bh+Bl)^T ----------------
// 128x128 tile, BK=32, 4 waves as 2x2, each wave 4x4 subtiles of 16x16x32.
// dot = hh + hl + lh (lo*lo dropped). Writes D row-major and optionally DT.
__global__ __launch_bounds__(256) void k_gemm_mfma(const _Float16* __restrict__ Ah,
                                                   const _Float16* __restrict__ Al,
                                                   const _Float16* __restrict__ Bh,
                                                   const _Float16* __restrict__ Bl,
                                                   float* __restrict__ D,
                                                   float* __restrict__ DT) {
  __shared__ __align__(16) _Float16 Ahs[128 * 32];
  __shared__ __align__(16) _Float16 Als[128 * 32];
  __shared__ __align__(16) _Float16 Bhs[128 * 32];
  __shared__ __align__(16) _Float16 Bls[128 * 32];
  const int t    = threadIdx.x;
  const int lane = t & 63, wave = t >> 6;
  const int wm = wave >> 1, wn = wave & 1;
  const int lm = lane & 15, q = lane >> 4;
  const int row0 = blockIdx.y * 128, col0 = blockIdx.x * 128;

  floatx4 acc[4][4];
#pragma unroll
  for (int i = 0; i < 4; ++i)
#pragma unroll
    for (int j = 0; j < 4; ++j) acc[i][j] = (floatx4){0.f, 0.f, 0.f, 0.f};

  // chunk assignment: chunk c (16B) of a [128][32]-half tile: row=c>>2, part=c&3
  const int r0 = t >> 2, p0 = t & 3;        // chunk t
  const int r1 = 64 + r0;                   // chunk t+256

  for (int k0 = 0; k0 < DIMK; k0 += 32) {
    size_t ga0 = (size_t)(row0 + r0) * DIMK + k0 + p0 * 8;
    size_t ga1 = (size_t)(row0 + r1) * DIMK + k0 + p0 * 8;
    size_t gb0 = (size_t)(col0 + r0) * DIMK + k0 + p0 * 8;
    size_t gb1 = (size_t)(col0 + r1) * DIMK + k0 + p0 * 8;
    half8 vah0 = *(const half8*)(Ah + ga0);
    half8 vah1 = *(const half8*)(Ah + ga1);
    half8 val0 = *(const half8*)(Al + ga0);
    half8 val1 = *(const half8*)(Al + ga1);
    half8 vbh0 = *(const half8*)(Bh + gb0);
    half8 vbh1 = *(const half8*)(Bh + gb1);
    half8 vbl0 = *(const half8*)(Bl + gb0);
    half8 vbl1 = *(const half8*)(Bl + gb1);
    __syncthreads();   // previous iteration's frag reads complete
    ((half8*)Ahs)[t] = vah0; ((half8*)Ahs)[t + 256] = vah1;
    ((half8*)Als)[t] = val0; ((half8*)Als)[t + 256] = val1;
    ((half8*)Bhs)[t] = vbh0; ((half8*)Bhs)[t + 256] = vbh1;
    ((half8*)Bls)[t] = vbl0; ((half8*)Bls)[t + 256] = vbl1;
    __syncthreads();

    half8 afh[4], afl[4], bfh[4], bfl[4];
#pragma unroll
    for (int i = 0; i < 4; ++i) {
      int ar = (wm * 64 + i * 16 + lm) * 32 + q * 8;
      int br = (wn * 64 + i * 16 + lm) * 32 + q * 8;
      afh[i] = *(const half8*)(Ahs + ar);
      afl[i] = *(const half8*)(Als + ar);
      bfh[i] = *(const half8*)(Bhs + br);
      bfl[i] = *(const half8*)(Bls + br);
    }
#pragma unroll
    for (int i = 0; i < 4; ++i)
#pragma unroll
      for (int j = 0; j < 4; ++j) {
        acc[i][j] = __builtin_amdgcn_mfma_f32_16x16x32_f16(afh[i], bfh[j], acc[i][j], 0, 0, 0);
        acc[i][j] = __builtin_amdgcn_mfma_f32_16x16x32_f16(afh[i], bfl[j], acc[i][j], 0, 0, 0);
        acc[i][j] = __builtin_amdgcn_mfma_f32_16x16x32_f16(afl[i], bfh[j], acc[i][j], 0, 0, 0);
      }
  }

  // epilogue: C/D layout col=lane&15, row=quad*4+reg (verified, dtype-independent)
#pragma unroll
  for (int i = 0; i < 4; ++i) {
    int mbase = row0 + wm * 64 + i * 16 + q * 4;
#pragma unroll
    for (int j = 0; j < 4; ++j) {
      int n = col0 + wn * 64 + j * 16 + lm;
      float vals[4];
#pragma unroll
      for (int r = 0; r < 4; ++r) {
        float vv = -TWO_S * acc[i][j][r];
        vals[r] = vv;
        D[(size_t)(mbase + r) * N_PTS + n] = vv;
      }
      if (DT) *(float4*)(DT + (size_t)n * N_PTS + mbase) = *(float4*)vals;
    }
  }
}

// ---------------- fp32 fallback GEMM (ws too small for halves) ----------------
__global__ __launch_bounds__(256) void k_gemm(const float* __restrict__ A,
                                              const float* __restrict__ B,
                                              float* __restrict__ D) {
  __shared__ float As[16][132];
  __shared__ float Bs[16][132];
  const int t  = threadIdx.x;
  const int tx = t & 15, ty = t >> 4;
  const int row0 = blockIdx.y * 128, col0 = blockIdx.x * 128;
  float acc[8][8];
#pragma unroll
  for (int i = 0; i < 8; ++i)
#pragma unroll
    for (int j = 0; j < 8; ++j) acc[i][j] = 0.f;
  for (int k0 = 0; k0 < DIMK; k0 += 16) {
#pragma unroll
    for (int s2 = 0; s2 < 2; ++s2) {
      int f4i = t + s2 * 256;
      int r   = f4i >> 2;
      int kp  = (f4i & 3) << 2;
      float4 a4 = *(const float4*)(A + (size_t)(row0 + r) * DIMK + k0 + kp);
      float4 b4 = *(const float4*)(B + (size_t)(col0 + r) * DIMK + k0 + kp);
      As[kp + 0][r] = a4.x; As[kp + 1][r] = a4.y; As[kp + 2][r] = a4.z; As[kp + 3][r] = a4.w;
      Bs[kp + 0][r] = b4.x; Bs[kp + 1][r] = b4.y; Bs[kp + 2][r] = b4.z; Bs[kp + 3][r] = b4.w;
    }
    __syncthreads();
#pragma unroll
    for (int kk = 0; kk < 16; ++kk) {
      float a[8], b[8];
      *(float4*)(a)     = *(const float4*)(&As[kk][ty * 4]);
      *(float4*)(a + 4) = *(const float4*)(&As[kk][64 + ty * 4]);
      *(float4*)(b)     = *(const float4*)(&Bs[kk][tx * 4]);
      *(float4*)(b + 4) = *(const float4*)(&Bs[kk][64 + tx * 4]);
#pragma unroll
      for (int i = 0; i < 8; ++i)
#pragma unroll
        for (int j = 0; j < 8; ++j) acc[i][j] = fmaf(a[i], b[j], acc[i][j]);
    }
    __syncthreads();
  }
#pragma unroll
  for (int i = 0; i < 8; ++i) {
    int r = row0 + ((i < 4) ? (ty * 4 + i) : (64 + ty * 4 + (i - 4)));
    float* out = D + (size_t)r * N_PTS + col0;
    float4 o1, o2;
    o1.x = -TWO_S * acc[i][0]; o1.y = -TWO_S * acc[i][1];
    o1.z = -TWO_S * acc[i][2]; o1.w = -TWO_S * acc[i][3];
    o2.x = -TWO_S * acc[i][4]; o2.y = -TWO_S * acc[i][5];
    o2.z = -TWO_S * acc[i][6]; o2.w = -TWO_S * acc[i][7];
    *(float4*)(out + tx * 4)      = o1;
    *(float4*)(out + 64 + tx * 4) = o2;
  }
}

// ---------------- generic coalesced row-LSE sweep: vout_r = 12 - log2 sum_c 2^(vin_c - M_rc) ----------------
// 1024 blocks x 256 threads; one wave per row (4 rows/block).
__global__ __launch_bounds__(256) void k_sweep(const float* __restrict__ Mrow,
                                               const float* __restrict__ vin,
                                               float* __restrict__ vout) {
  const int t = threadIdx.x;
  const int l = t & 63;
  const int row = blockIdx.x * 4 + (t >> 6);
  const float* rp_ = Mrow + (size_t)row * N_PTS;
  float M = NEG_BIG, S = 0.f;
#pragma unroll
  for (int c = 0; c < 4; ++c) {
    float v[16];
#pragma unroll
    for (int qq = 0; qq < 4; ++qq) {
      int j = l * 4 + (c * 4 + qq) * 256;
      float4 d = *(const float4*)(rp_ + j);
      float4 g = *(const float4*)(vin + j);
      v[qq * 4 + 0] = g.x - d.x;
      v[qq * 4 + 1] = g.y - d.y;
      v[qq * 4 + 2] = g.z - d.z;
      v[qq * 4 + 3] = g.w - d.w;
    }
    float Mc = v[0];
#pragma unroll
    for (int qq = 1; qq < 16; ++qq) Mc = fmaxf(Mc, v[qq]);
    float Mn = fmaxf(M, Mc);
    float s  = S * exp2f(M - Mn);
#pragma unroll
    for (int qq = 0; qq < 16; ++qq) s += exp2f(v[qq] - Mn);
    M = Mn; S = s;
  }
#pragma unroll
  for (int off = 32; off; off >>= 1) {
    float M2 = __shfl_xor(M, off);
    float S2 = __shfl_xor(S, off);
    float Mn = fmaxf(M, M2);
    S = S * exp2f(M - Mn) + S2 * exp2f(M2 - Mn);
    M = Mn;
  }
  if (l == 0) vout[row] = 12.0f - M - log2f(S);
}

// ---------------- fallback column LSE (gather) if no DT ----------------
__device__ __forceinline__ float4 f4max(float4 a, float4 b) {
  return make_float4(fmaxf(a.x, b.x), fmaxf(a.y, b.y), fmaxf(a.z, b.z), fmaxf(a.w, b.w));
}
__device__ __forceinline__ void msmerge(float4& M, float4& S, const float4 M2, const float4 S2) {
  float4 Mn = f4max(M, M2);
  S.x = S.x * exp2f(M.x - Mn.x) + S2.x * exp2f(M2.x - Mn.x);
  S.y = S.y * exp2f(M.y - Mn.y) + S2.y * exp2f(M2.y - Mn.y);
  S.z = S.z * exp2f(M.z - Mn.z) + S2.z * exp2f(M2.z - Mn.z);
  S.w = S.w * exp2f(M.w - Mn.w) + S2.w * exp2f(M2.w - Mn.w);
  M = Mn;
}
__global__ __launch_bounds__(1024) void k_colpass(const float* __restrict__ D,
                                                  const float* __restrict__ fvec,
                                                  float* __restrict__ gvec) {
  __shared__ float fs[N_PTS];
  __shared__ float4 MS[16][4][2];
  const int t = threadIdx.x;
  *(float4*)(fs + t * 4) = *(const float4*)(fvec + t * 4);
  __syncthreads();
  const int c4 = t & 3;
  const int rp = t >> 2;
  const float* base = D + blockIdx.x * 16 + c4 * 4;
  float4 M = make_float4(NEG_BIG, NEG_BIG, NEG_BIG, NEG_BIG);
  float4 S = make_float4(0.f, 0.f, 0.f, 0.f);
#pragma unroll
  for (int h = 0; h < 2; ++h) {
    float4 v[8];
#pragma unroll
    for (int qq = 0; qq < 8; ++qq) {
      int r = rp + (h * 8 + qq) * 256;
      float4 d = *(const float4*)(base + (size_t)r * N_PTS);
      float fr = fs[r];
      v[qq] = make_float4(fr - d.x, fr - d.y, fr - d.z, fr - d.w);
    }
    float4 Mc = f4max(f4max(f4max(v[0], v[1]), f4max(v[2], v[3])),
                      f4max(f4max(v[4], v[5]), f4max(v[6], v[7])));
    float4 Mn = f4max(M, Mc);
    float4 s;
    s.x = S.x * exp2f(M.x - Mn.x);
    s.y = S.y * exp2f(M.y - Mn.y);
    s.z = S.z * exp2f(M.z - Mn.z);
    s.w = S.w * exp2f(M.w - Mn.w);
#pragma unroll
    for (int qq = 0; qq < 8; ++qq) {
      s.x += exp2f(v[qq].x - Mn.x);
      s.y += exp2f(v[qq].y - Mn.y);
      s.z += exp2f(v[qq].z - Mn.z);
      s.w += exp2f(v[qq].w - Mn.w);
    }
    M = Mn; S = s;
  }
#pragma unroll
  for (int off = 4; off <= 32; off <<= 1) {
    float4 M2, S2;
    M2.x = __shfl_xor(M.x, off); M2.y = __shfl_xor(M.y, off);
    M2.z = __shfl_xor(M.z, off); M2.w = __shfl_xor(M.w, off);
    S2.x = __shfl_xor(S.x, off); S2.y = __shfl_xor(S.y, off);
    S2.z = __shfl_xor(S.z, off); S2.w = __shfl_xor(S.w, off);
    msmerge(M, S, M2, S2);
  }
  const int wv = t >> 6, l = t & 63;
  if (l < 4) { MS[wv][l][0] = M; MS[wv][l][1] = S; }
  __syncthreads();
  if (t < 4) {
    float4 M0 = MS[0][t][0], S0 = MS[0][t][1];
#pragma unroll
    for (int w = 1; w < 16; ++w) msmerge(M0, S0, MS[w][t][0], MS[w][t][1]);
    float4 g;
    g.x = 12.0f - M0.x - log2f(S0.x);
    g.y = 12.0f - M0.y - log2f(S0.y);
    g.z = 12.0f - M0.z - log2f(S0.z);
    g.w = 12.0f - M0.w - log2f(S0.w);
    *(float4*)(gvec + blockIdx.x * 16 + t * 4) = g;
  }
}

// ---------------- final: P = exp2(0.1*(f_i + g_j - D_ij)), in place ----------------
__global__ __launch_bounds__(256) void k_final(float* __restrict__ D,
                                               const float* __restrict__ fvec,
                                               const float* __restrict__ gvec) {
  size_t idx = ((size_t)blockIdx.x * 256 + threadIdx.x) * 8;
  int i = (int)(idx >> 12);
  int j = (int)(idx & (N_PTS - 1));
  float fi = fvec[i];
#pragma unroll
  for (int h = 0; h < 2; ++h) {
    float4 d  = *(float4*)(D + idx + h * 4);
    float4 g4 = *(const float4*)(gvec + j + h * 4);
    d.x = exp2f(0.1f * (fi + g4.x - d.x));
    d.y = exp2f(0.1f * (fi + g4.y - d.y));
    d.z = exp2f(0.1f * (fi + g4.z - d.z));
    d.w = exp2f(0.1f * (fi + g4.w - d.w));
    *(float4*)(D + idx + h * 4) = d;
  }
}

extern "C" void kernel_launch(void* const* d_in, const int* in_sizes, int n_in,
                              void* d_out, int out_size, void* d_ws, size_t ws_size,
                              hipStream_t stream) {
  const float* Xs = (const float*)d_in[0];
  const float* Xt = (const float*)d_in[1];
  float* D   = (float*)d_out;
  char* wsb  = (char*)d_ws;
  float* fvec = (float*)wsb;
  float* gvec = fvec + N_PTS;

  const size_t halfElems  = (size_t)N_PTS * DIMK;           // 4 Mi halves each
  const size_t offHalves  = 32768;
  _Float16* Ah = (_Float16*)(wsb + offHalves);
  _Float16* Al = Ah + halfElems;
  _Float16* Bh = Al + halfElems;
  _Float16* Bl = Bh + halfElems;
  float* DT    = (float*)(wsb + offHalves + 4 * halfElems * sizeof(_Float16));
  const size_t needHalves = offHalves + 4 * halfElems * sizeof(_Float16);          // ~32.03 MB
  const size_t needFull   = needHalves + (size_t)N_PTS * N_PTS * sizeof(float);    // +64 MB
  const bool haveH = ws_size >= needHalves;
  const bool haveT = ws_size >= needFull;

  k_prep<<<1024, 256, 0, stream>>>(Xs, fvec);
  if (haveH) {
    k_convert<<<2048, 256, 0, stream>>>(Xs, Ah, Al);
    k_convert<<<2048, 256, 0, stream>>>(Xt, Bh, Bl);
    k_gemm_mfma<<<dim3(32, 32), 256, 0, stream>>>(Ah, Al, Bh, Bl, D, haveT ? DT : nullptr);
  } else {
    k_gemm<<<dim3(32, 32), 256, 0, stream>>>(Xs, Xt, D);
  }
  for (int it = 0; it < 30; ++it) {
    if (haveT) k_sweep<<<1024, 256, 0, stream>>>(DT, fvec, gvec);
    else       k_colpass<<<256, 1024, 0, stream>>>(D, fvec, gvec);
    k_sweep<<<1024, 256, 0, stream>>>(D, gvec, fvec);
  }
  k_final<<<8192, 256, 0, stream>>>(D, fvec, gvec);
}